// Round 8
// baseline (325.403 us; speedup 1.0000x reference)
//
#include <hip/hip_runtime.h>

// YOLO loss, round 14: r10 (best: ~52.5us main) + fused final reduction.
//
// r13 post-mortem: persistent depth-2 DMA pipeline = 73us, occupancy 10%
// -> duty-cycle theory REFUTED: killing TLP lowered the read rate. Eight
// structures now bracket the truth: delivered read traffic converges to
// ~3.2 TB/s (r11 dense: 176.6MB/55us) while the same runs WRITE 6.8 TB/s
// (fillBuffer) and m13's 6.29 copy = R+W = ~3.15/direction. The READ
// path serves ~3.2 TB/s, period. r10 (fewer bytes, slight scatter
// penalty, 52.5us) and r11 (more bytes, full rate, 55us) both sit within
// ~5% of this ceiling -> main kernel is at its roofline.
// Also: r13's FETCH=86MB < dense 176.6MB proves L3 absorbs ~half the
// input across iterations; FETCH is HBM-only, delivered rate is the
// meaningful number.
//
// r14 claims the last owned overhead: the separate 1-block yolo_final
// launch (~4-8us). Last-block-done ticket (threadfence + device atomic
// counter, zeroed by 4B hipMemsetAsync after harness poison); reducing
// block replicates yolo_final's exact summation order -> bit-identical.
// Predict: total 191.8 -> ~185-188, main ~55-58 (absorbs reduce).
// If >=191: fusion neutral, kernel == best known -> ROOFLINE.

#define SS 28
#define BLOCK 256
#define WAVES (BLOCK / 64)

typedef const __attribute__((address_space(1))) void* as1cp;
typedef __attribute__((address_space(3))) void* as3p;
typedef float f32x4 __attribute__((ext_vector_type(4)));

__global__ __launch_bounds__(BLOCK) void yolo_main(
    const float4* __restrict__ pred4,   // [cells*30/4]
    const float4* __restrict__ tbox4,   // [cells]
    const float4* __restrict__ tcls4,   // [cells*5]
    const int*   __restrict__ mask,     // [cells]
    float4* __restrict__ block_part,    // [gridDim.x]
    unsigned*    __restrict__ counter,  // zeroed before launch
    float*       __restrict__ out,      // [5]
    float invN,
    int cells)
{
    __shared__ float  spred[WAVES][64 * 30];   // 4 x 7680 B
    __shared__ float4 sred[WAVES];
    __shared__ int    slast;

    const int tid    = threadIdx.x;
    const int lane   = tid & 63;
    const int wid    = tid >> 6;
    const int wcell0 = blockIdx.x * BLOCK + wid * 64;  // wave's first cell
    const int cell   = wcell0 + lane;

    int m = 0;
    if (cell < cells) m = __builtin_nontemporal_load(mask + cell);

    float* sp = spred[wid];
    const size_t pb4  = (size_t)wcell0 * 30 / 4;
    const size_t lim4 = (size_t)cells * 30 / 4;

    // ---- pred staging: 8 gated async DMA float4 loads, no VGPRs ----
    // (gating exact per r8-r10, absmax=0: mask=0 records keep only the two
    //  float4s containing comps 4 and 9 = one contiguous 32B chunk)
    #pragma unroll
    for (int it = 0; it < 8; ++it) {
        int p  = it * 64 + lane;            // 0..543, valid < 480
        int f0 = 4 * p;
        int c0 = f0 / 30;
        int c3 = (f0 + 3) / 30;
        int r0 = f0 - 30 * c0;
        int m0 = __shfl(m, c0 > 63 ? 63 : c0, 64);
        int m3 = __shfl(m, c3 > 63 ? 63 : c3, 64);
        bool need = (p < 480) && (pb4 + (size_t)p < lim4) &&
                    ((m0 | m3) || (r0 >= 1 && r0 <= 4) || (r0 >= 6 && r0 <= 9));
        if (need) {
            __builtin_amdgcn_global_load_lds(
                (as1cp)(pred4 + pb4 + p),
                (as3p)(sp + it * 256),
                16, 0, 0);
        }
    }

    // ---- tbox: DENSE sequential (1KB/wave), nontemporal ----
    float4 tb = make_float4(0.f, 0.f, 0.f, 0.f);
    if (cell < cells) {
        f32x4 tv = __builtin_nontemporal_load((const f32x4*)(tbox4 + cell));
        tb.x = tv[0]; tb.y = tv[1]; tb.z = tv[2]; tb.w = tv[3];
    }

    // ---- tcls: transposed unit-stride float4, gated, NT, 5 named slots ----
    const size_t tq0 = (size_t)wcell0 * 5;
    float4 t0v, t1v, t2v, t3v, t4v;
    int n0, n1, n2, n3, n4;
    int c0_, c1_, c2_, c3_, c4_;
    int k0_, k1_, k2_, k3_, k4_;
#define TCLS_ISSUE(I, TT, NN, CC, KK)                                   \
    {                                                                   \
        int q = (I) * 64 + lane;                                        \
        int c = q / 5;                                                  \
        int k = q - 5 * c;                                              \
        int mc = __shfl(m, c, 64);                                      \
        NN = mc; CC = c; KK = k;                                        \
        TT = make_float4(0.f, 0.f, 0.f, 0.f);                           \
        if (mc) {                                                       \
            f32x4 tv = __builtin_nontemporal_load(                      \
                (const f32x4*)(tcls4 + tq0 + q));                       \
            TT.x = tv[0]; TT.y = tv[1]; TT.z = tv[2]; TT.w = tv[3];     \
        }                                                               \
    }
    TCLS_ISSUE(0, t0v, n0, c0_, k0_)
    TCLS_ISSUE(1, t1v, n1, c1_, k1_)
    TCLS_ISSUE(2, t2v, n2, c2_, k2_)
    TCLS_ISSUE(3, t3v, n3, c3_, k3_)
    TCLS_ISSUE(4, t4v, n4, c4_, k4_)
#undef TCLS_ISSUE

    // drain all in-flight requests (global_load_lds is vmcnt-tracked)
    asm volatile("s_waitcnt vmcnt(0)" ::: "memory");
    __builtin_amdgcn_sched_barrier(0);

    float acc_cls = 0.f, acc_noobj = 0.f, acc_reg = 0.f, acc_cont = 0.f;

    // ---- per-cell compute (pred from own LDS slice) ----
    if (cell < cells) {
        const float* pr = sp + lane * 30;
        if (!m) {
            float c1 = pr[4], c2 = pr[9];
            acc_noobj = c1 * c1 + c2 * c2;          // *0.5 in finalize
        } else {
            const float invS = 1.f / 28.f;
            float txc = tb.x * invS, tyc = tb.y * invS;
            float t0 = txc - 0.5f * tb.z, t1 = tyc - 0.5f * tb.w;
            float t2 = txc + 0.5f * tb.z, t3 = tyc + 0.5f * tb.w;
            float ta = (t2 - t0) * (t3 - t1);

            float b1xc = pr[0] * invS, b1yc = pr[1] * invS;
            float a0 = b1xc - 0.5f * pr[2], a1 = b1yc - 0.5f * pr[3];
            float a2 = b1xc + 0.5f * pr[2], a3 = b1yc + 0.5f * pr[3];
            float wx = fmaxf(fminf(a2, t2) - fmaxf(a0, t0), 0.f);
            float wy = fmaxf(fminf(a3, t3) - fmaxf(a1, t1), 0.f);
            float inter = wx * wy;
            float area1 = (a2 - a0) * (a3 - a1);
            float den = area1 + ta - inter;
            float iou1 = inter / (den > 0.f ? den : 1.f);

            float b2xc = pr[5] * invS, b2yc = pr[6] * invS;
            float e0 = b2xc - 0.5f * pr[7], e1 = b2yc - 0.5f * pr[8];
            float e2 = b2xc + 0.5f * pr[7], e3 = b2yc + 0.5f * pr[8];
            wx = fmaxf(fminf(e2, t2) - fmaxf(e0, t0), 0.f);
            wy = fmaxf(fminf(e3, t3) - fmaxf(e1, t1), 0.f);
            inter = wx * wy;
            float area2 = (e2 - e0) * (e3 - e1);
            den = area2 + ta - inter;
            float iou2 = inter / (den > 0.f ? den : 1.f);

            bool take1 = iou1 > iou2;
            float best_iou = take1 ? iou1 : iou2;
            float bbx = take1 ? pr[0] : pr[5];
            float bby = take1 ? pr[1] : pr[6];
            float bbw = take1 ? pr[2] : pr[7];
            float bbh = take1 ? pr[3] : pr[8];
            float bbc = take1 ? pr[4] : pr[9];

            float dx = bbx - tb.x, dy = bby - tb.y;
            float xy = dx * dx + dy * dy;

            float dw = sqrtf(bbw) - sqrtf(tb.z);    // mask==1: where() == value
            float dh = sqrtf(bbh) - sqrtf(tb.w);
            float wh = dw * dw + dh * dh;

            acc_reg = xy + wh;

            float dc = bbc - best_iou;
            acc_cont = dc * dc;
        }
    }

    // ---- cls loss (tcls regs vs LDS pred) ----
#define TCLS_USE(TT, NN, CC, KK)                                  \
    if (NN) {                                                     \
        const float* pp = sp + CC * 30 + 10 + 4 * KK;             \
        float d0 = pp[0] - TT.x, d1 = pp[1] - TT.y;               \
        float d2 = pp[2] - TT.z, d3 = pp[3] - TT.w;               \
        acc_cls += d0 * d0 + d1 * d1 + d2 * d2 + d3 * d3;         \
    }
    TCLS_USE(t0v, n0, c0_, k0_)
    TCLS_USE(t1v, n1, c1_, k1_)
    TCLS_USE(t2v, n2, c2_, k2_)
    TCLS_USE(t3v, n3, c3_, k3_)
    TCLS_USE(t4v, n4, c4_, k4_)
#undef TCLS_USE

    // ---- wave + block reduction ----
    float4 vr = make_float4(acc_cls, acc_noobj, acc_reg, acc_cont);
    #pragma unroll
    for (int off = 32; off >= 1; off >>= 1) {
        vr.x += __shfl_down(vr.x, off, 64);
        vr.y += __shfl_down(vr.y, off, 64);
        vr.z += __shfl_down(vr.z, off, 64);
        vr.w += __shfl_down(vr.w, off, 64);
    }
    if (lane == 0) sred[wid] = vr;
    __syncthreads();
    if (tid == 0) {
        float4 r = sred[0];
        #pragma unroll
        for (int w = 1; w < WAVES; ++w) {
            r.x += sred[w].x; r.y += sred[w].y; r.z += sred[w].z; r.w += sred[w].w;
        }
        block_part[blockIdx.x] = r;
        // last-block-done ticket: make partial visible, then count
        __threadfence();
        unsigned done = atomicAdd(counter, 1u);
        slast = (done == gridDim.x - 1) ? 1 : 0;
    }
    __syncthreads();

    // ---- fused final reduction (exact yolo_final order -> bit-identical) ----
    if (slast) {
        int nparts = gridDim.x;
        float4 v = make_float4(0.f, 0.f, 0.f, 0.f);
        for (int i = tid; i < nparts; i += BLOCK) {
            float4 p = block_part[i];
            v.x += p.x; v.y += p.y; v.z += p.z; v.w += p.w;
        }
        #pragma unroll
        for (int off = 32; off >= 1; off >>= 1) {
            v.x += __shfl_down(v.x, off, 64);
            v.y += __shfl_down(v.y, off, 64);
            v.z += __shfl_down(v.z, off, 64);
            v.w += __shfl_down(v.w, off, 64);
        }
        if (lane == 0) sred[wid] = v;
        __syncthreads();
        if (tid == 0) {
            float4 r = sred[0];
            #pragma unroll
            for (int w = 1; w < WAVES; ++w) {
                r.x += sred[w].x; r.y += sred[w].y; r.z += sred[w].z; r.w += sred[w].w;
            }
            float cls    = r.x;
            float no_obj = 0.5f * r.y;   // L_NOOBJ
            float reg    = 5.0f * r.z;   // L_COORD
            float cont   = r.w;
            float total  = cls + no_obj + cont + reg;
            out[0] = total  * invN;
            out[1] = reg    * invN;
            out[2] = cont   * invN;
            out[3] = no_obj * invN;
            out[4] = cls    * invN;
        }
    }
}

extern "C" void kernel_launch(void* const* d_in, const int* in_sizes, int n_in,
                              void* d_out, int out_size, void* d_ws, size_t ws_size,
                              hipStream_t stream) {
    const float* pred = (const float*)d_in[0];
    const float* tbox = (const float*)d_in[1];
    const float* tcls = (const float*)d_in[2];
    const int*   mask = (const int*)d_in[3];
    float* out = (float*)d_out;

    int cells = in_sizes[0] / 30;                 // N*S*S = 802816
    int n_img = cells / (SS * SS);                // N
    int nblocks = (cells + BLOCK - 1) / BLOCK;    // 3136

    float4*   part    = (float4*)d_ws;            // nblocks * 16 bytes
    unsigned* counter = (unsigned*)(part + nblocks);

    hipMemsetAsync(counter, 0, sizeof(unsigned), stream);

    yolo_main<<<nblocks, BLOCK, 0, stream>>>(
        (const float4*)pred, (const float4*)tbox, (const float4*)tcls,
        mask, part, counter, out, 1.0f / (float)n_img, cells);
}

// Round 9
// 190.371 us; speedup vs baseline: 1.7093x; 1.7093x over previous
//
#include <hip/hip_runtime.h>

// YOLO loss, round 15: REVERT to r10 — best measured (191.8us total,
// main ~52.5us). r14's last-block fusion was catastrophic (+120us):
// per-block __threadfence() on non-coherent multi-XCD L2 forces an L2
// writeback per block (3136x), serializing the memory controllers and
// collapsing delivered read BW to ~1 TB/s. ANTI-PATTERN: last-block-done
// fusion under BW-bound main kernels on CDNA4; a 2nd launch (~5us) is
// far cheaper than device-scope fences.
//
// Final model (9 structures, 2 sessions):
//  - read-path service ceiling ~3.2 TB/s delivered (r11 dense 176.6MB/55us;
//    fillBuffer WRITES 6.8 TB/s on same runs; m13 copy R+W ~3.15/dir).
//  - r10 (gated ~147MB effective, slight scatter penalty, 52.5us) and
//    r11 (dense 176.6MB full-rate, 55us) bracket the optimum within ~5%.
//  - refuted: transaction-count theory (r7), MLP/duty-cycle theory (r13),
//    occupancy sensitivity (r6 57% == r9 38%), fusion (r14).
// This kernel = byte-shaped variant: gated DMA pred staging (mask=0
// records fetch only the 32B holding comps 4/9), dense NT tbox, gated
// transposed NT tcls, wave-private LDS, no block barriers.

#define SS 28
#define BLOCK 256
#define WAVES (BLOCK / 64)

typedef const __attribute__((address_space(1))) void* as1cp;
typedef __attribute__((address_space(3))) void* as3p;
typedef float f32x4 __attribute__((ext_vector_type(4)));

__global__ __launch_bounds__(BLOCK) void yolo_main(
    const float4* __restrict__ pred4,   // [cells*30/4]
    const float4* __restrict__ tbox4,   // [cells]
    const float4* __restrict__ tcls4,   // [cells*5]
    const int*   __restrict__ mask,     // [cells]
    float4* __restrict__ block_part,    // [gridDim.x]
    int cells)
{
    __shared__ float  spred[WAVES][64 * 30];   // 4 x 7680 B
    __shared__ float4 sred[WAVES];

    const int tid    = threadIdx.x;
    const int lane   = tid & 63;
    const int wid    = tid >> 6;
    const int wcell0 = blockIdx.x * BLOCK + wid * 64;  // wave's first cell
    const int cell   = wcell0 + lane;

    int m = 0;
    if (cell < cells) m = __builtin_nontemporal_load(mask + cell);

    float* sp = spred[wid];
    const size_t pb4  = (size_t)wcell0 * 30 / 4;
    const size_t lim4 = (size_t)cells * 30 / 4;

    // ---- pred staging: 8 gated async DMA float4 loads, no VGPRs ----
    // (gating exact per r8-r10, absmax=0: mask=0 records keep only the two
    //  float4s containing comps 4 and 9 = one contiguous 32B chunk)
    #pragma unroll
    for (int it = 0; it < 8; ++it) {
        int p  = it * 64 + lane;            // 0..543, valid < 480
        int f0 = 4 * p;
        int c0 = f0 / 30;
        int c3 = (f0 + 3) / 30;
        int r0 = f0 - 30 * c0;
        int m0 = __shfl(m, c0 > 63 ? 63 : c0, 64);
        int m3 = __shfl(m, c3 > 63 ? 63 : c3, 64);
        bool need = (p < 480) && (pb4 + (size_t)p < lim4) &&
                    ((m0 | m3) || (r0 >= 1 && r0 <= 4) || (r0 >= 6 && r0 <= 9));
        if (need) {
            __builtin_amdgcn_global_load_lds(
                (as1cp)(pred4 + pb4 + p),
                (as3p)(sp + it * 256),
                16, 0, 0);
        }
    }

    // ---- tbox: DENSE sequential (1KB/wave), nontemporal ----
    float4 tb = make_float4(0.f, 0.f, 0.f, 0.f);
    if (cell < cells) {
        f32x4 tv = __builtin_nontemporal_load((const f32x4*)(tbox4 + cell));
        tb.x = tv[0]; tb.y = tv[1]; tb.z = tv[2]; tb.w = tv[3];
    }

    // ---- tcls: transposed unit-stride float4, gated, NT, 5 named slots ----
    const size_t tq0 = (size_t)wcell0 * 5;
    float4 t0v, t1v, t2v, t3v, t4v;
    int n0, n1, n2, n3, n4;
    int c0_, c1_, c2_, c3_, c4_;
    int k0_, k1_, k2_, k3_, k4_;
#define TCLS_ISSUE(I, TT, NN, CC, KK)                                   \
    {                                                                   \
        int q = (I) * 64 + lane;                                        \
        int c = q / 5;                                                  \
        int k = q - 5 * c;                                              \
        int mc = __shfl(m, c, 64);                                      \
        NN = mc; CC = c; KK = k;                                        \
        TT = make_float4(0.f, 0.f, 0.f, 0.f);                           \
        if (mc) {                                                       \
            f32x4 tv = __builtin_nontemporal_load(                      \
                (const f32x4*)(tcls4 + tq0 + q));                       \
            TT.x = tv[0]; TT.y = tv[1]; TT.z = tv[2]; TT.w = tv[3];     \
        }                                                               \
    }
    TCLS_ISSUE(0, t0v, n0, c0_, k0_)
    TCLS_ISSUE(1, t1v, n1, c1_, k1_)
    TCLS_ISSUE(2, t2v, n2, c2_, k2_)
    TCLS_ISSUE(3, t3v, n3, c3_, k3_)
    TCLS_ISSUE(4, t4v, n4, c4_, k4_)
#undef TCLS_ISSUE

    // drain all in-flight requests (global_load_lds is vmcnt-tracked)
    asm volatile("s_waitcnt vmcnt(0)" ::: "memory");
    __builtin_amdgcn_sched_barrier(0);

    float acc_cls = 0.f, acc_noobj = 0.f, acc_reg = 0.f, acc_cont = 0.f;

    // ---- per-cell compute (pred from own LDS slice) ----
    if (cell < cells) {
        const float* pr = sp + lane * 30;
        if (!m) {
            float c1 = pr[4], c2 = pr[9];
            acc_noobj = c1 * c1 + c2 * c2;          // *0.5 in finalize
        } else {
            const float invS = 1.f / 28.f;
            float txc = tb.x * invS, tyc = tb.y * invS;
            float t0 = txc - 0.5f * tb.z, t1 = tyc - 0.5f * tb.w;
            float t2 = txc + 0.5f * tb.z, t3 = tyc + 0.5f * tb.w;
            float ta = (t2 - t0) * (t3 - t1);

            float b1xc = pr[0] * invS, b1yc = pr[1] * invS;
            float a0 = b1xc - 0.5f * pr[2], a1 = b1yc - 0.5f * pr[3];
            float a2 = b1xc + 0.5f * pr[2], a3 = b1yc + 0.5f * pr[3];
            float wx = fmaxf(fminf(a2, t2) - fmaxf(a0, t0), 0.f);
            float wy = fmaxf(fminf(a3, t3) - fmaxf(a1, t1), 0.f);
            float inter = wx * wy;
            float area1 = (a2 - a0) * (a3 - a1);
            float den = area1 + ta - inter;
            float iou1 = inter / (den > 0.f ? den : 1.f);

            float b2xc = pr[5] * invS, b2yc = pr[6] * invS;
            float e0 = b2xc - 0.5f * pr[7], e1 = b2yc - 0.5f * pr[8];
            float e2 = b2xc + 0.5f * pr[7], e3 = b2yc + 0.5f * pr[8];
            wx = fmaxf(fminf(e2, t2) - fmaxf(e0, t0), 0.f);
            wy = fmaxf(fminf(e3, t3) - fmaxf(e1, t1), 0.f);
            inter = wx * wy;
            float area2 = (e2 - e0) * (e3 - e1);
            den = area2 + ta - inter;
            float iou2 = inter / (den > 0.f ? den : 1.f);

            bool take1 = iou1 > iou2;
            float best_iou = take1 ? iou1 : iou2;
            float bbx = take1 ? pr[0] : pr[5];
            float bby = take1 ? pr[1] : pr[6];
            float bbw = take1 ? pr[2] : pr[7];
            float bbh = take1 ? pr[3] : pr[8];
            float bbc = take1 ? pr[4] : pr[9];

            float dx = bbx - tb.x, dy = bby - tb.y;
            float xy = dx * dx + dy * dy;

            float dw = sqrtf(bbw) - sqrtf(tb.z);    // mask==1: where() == value
            float dh = sqrtf(bbh) - sqrtf(tb.w);
            float wh = dw * dw + dh * dh;

            acc_reg = xy + wh;

            float dc = bbc - best_iou;
            acc_cont = dc * dc;
        }
    }

    // ---- cls loss (tcls regs vs LDS pred) ----
#define TCLS_USE(TT, NN, CC, KK)                                  \
    if (NN) {                                                     \
        const float* pp = sp + CC * 30 + 10 + 4 * KK;             \
        float d0 = pp[0] - TT.x, d1 = pp[1] - TT.y;               \
        float d2 = pp[2] - TT.z, d3 = pp[3] - TT.w;               \
        acc_cls += d0 * d0 + d1 * d1 + d2 * d2 + d3 * d3;         \
    }
    TCLS_USE(t0v, n0, c0_, k0_)
    TCLS_USE(t1v, n1, c1_, k1_)
    TCLS_USE(t2v, n2, c2_, k2_)
    TCLS_USE(t3v, n3, c3_, k3_)
    TCLS_USE(t4v, n4, c4_, k4_)
#undef TCLS_USE

    // ---- wave + block reduction ----
    float4 vr = make_float4(acc_cls, acc_noobj, acc_reg, acc_cont);
    #pragma unroll
    for (int off = 32; off >= 1; off >>= 1) {
        vr.x += __shfl_down(vr.x, off, 64);
        vr.y += __shfl_down(vr.y, off, 64);
        vr.z += __shfl_down(vr.z, off, 64);
        vr.w += __shfl_down(vr.w, off, 64);
    }
    if (lane == 0) sred[wid] = vr;
    __syncthreads();
    if (tid == 0) {
        float4 r = sred[0];
        #pragma unroll
        for (int w = 1; w < WAVES; ++w) {
            r.x += sred[w].x; r.y += sred[w].y; r.z += sred[w].z; r.w += sred[w].w;
        }
        block_part[blockIdx.x] = r;
    }
}

__global__ __launch_bounds__(BLOCK) void yolo_final(
    const float4* __restrict__ part, int nparts, float* __restrict__ out, float invN)
{
    float4 v = make_float4(0.f, 0.f, 0.f, 0.f);
    for (int i = threadIdx.x; i < nparts; i += BLOCK) {
        float4 p = part[i];
        v.x += p.x; v.y += p.y; v.z += p.z; v.w += p.w;
    }
    #pragma unroll
    for (int off = 32; off >= 1; off >>= 1) {
        v.x += __shfl_down(v.x, off, 64);
        v.y += __shfl_down(v.y, off, 64);
        v.z += __shfl_down(v.z, off, 64);
        v.w += __shfl_down(v.w, off, 64);
    }
    __shared__ float4 sred[BLOCK / 64];
    int lane = threadIdx.x & 63;
    int wave = threadIdx.x >> 6;
    if (lane == 0) sred[wave] = v;
    __syncthreads();
    if (threadIdx.x == 0) {
        float4 r = sred[0];
        #pragma unroll
        for (int w = 1; w < BLOCK / 64; ++w) {
            r.x += sred[w].x; r.y += sred[w].y; r.z += sred[w].z; r.w += sred[w].w;
        }
        float cls    = r.x;
        float no_obj = 0.5f * r.y;   // L_NOOBJ
        float reg    = 5.0f * r.z;   // L_COORD
        float cont   = r.w;
        float total  = cls + no_obj + cont + reg;
        out[0] = total  * invN;
        out[1] = reg    * invN;
        out[2] = cont   * invN;
        out[3] = no_obj * invN;
        out[4] = cls    * invN;
    }
}

extern "C" void kernel_launch(void* const* d_in, const int* in_sizes, int n_in,
                              void* d_out, int out_size, void* d_ws, size_t ws_size,
                              hipStream_t stream) {
    const float* pred = (const float*)d_in[0];
    const float* tbox = (const float*)d_in[1];
    const float* tcls = (const float*)d_in[2];
    const int*   mask = (const int*)d_in[3];
    float* out = (float*)d_out;

    int cells = in_sizes[0] / 30;                 // N*S*S = 802816
    int n_img = cells / (SS * SS);                // N
    int nblocks = (cells + BLOCK - 1) / BLOCK;    // 3136

    float4* part = (float4*)d_ws;                 // nblocks * 16 bytes

    yolo_main<<<nblocks, BLOCK, 0, stream>>>(
        (const float4*)pred, (const float4*)tbox, (const float4*)tcls,
        mask, part, cells);
    yolo_final<<<1, BLOCK, 0, stream>>>(part, nblocks, out, 1.0f / (float)n_img);
}